// Round 2
// baseline (1261.909 us; speedup 1.0000x reference)
//
#include <hip/hip_runtime.h>

#define BB 64
#define LL 512
#define DD 1024
#define CC 131
#define CP 132
#define START_I 129
#define STOP_I 130
#define NEGV -10000.0f

// Raw workgroup barrier: makes LDS writes visible without draining vmcnt
// (so global stores/prefetches stay in flight across steps).
__device__ __forceinline__ void lds_barrier() {
    asm volatile("s_waitcnt lgkmcnt(0)" ::: "memory");
    __builtin_amdgcn_s_barrier();
    __builtin_amdgcn_sched_barrier(0);
}

// ---------------- Kernel 1: feats[m][c] = dot(x[m,:], W[c,:]) + b[c] ----------------
// 256 blocks x 256 threads. Block tile 128m x 131j, thread tile 8m x 8j (+3-col tail
// for tj<3). LDS [row][k] stride 36 floats (144B, 16B-aligned, 2-way banks = free).
#define GM 128
#define GK 32
#define LSTR 36

__global__ __launch_bounds__(256, 1) void gemm_feats(
    const float* __restrict__ x, const float* __restrict__ W,
    const float* __restrict__ bias, float* __restrict__ feats)
{
    __shared__ float xs[GM * LSTR];   // [m][k]
    __shared__ float ws[CP * LSTR];   // [j][k]

    const int tid = threadIdx.x;
    const int m0 = blockIdx.x * GM;
    const int tm = tid & 15;          // m-thread  (rows tm + 16r)
    const int tj = (tid >> 4) & 15;   // j-thread  (cols tj + 16c)
    const bool tail = (tj < 3);
    const int tjt = (tj < 3) ? tj : 2;

    float acc[8][8];
    float acct[8];
#pragma unroll
    for (int r = 0; r < 8; ++r) {
        acct[r] = 0.f;
#pragma unroll
        for (int c = 0; c < 8; ++c) acc[r][c] = 0.f;
    }

    for (int kc = 0; kc < DD / GK; ++kc) {
        const int k0 = kc * GK;
        if (kc) __syncthreads();
        // stage x: 128 rows x 32 k = 1024 float4 (coalesced global, aligned LDS f4)
#pragma unroll
        for (int q = 0; q < 4; ++q) {
            int lin = tid + q * 256;
            int m = lin >> 3, c4 = lin & 7;
            float4 v = *(const float4*)&x[(size_t)(m0 + m) * DD + k0 + c4 * 4];
            *(float4*)&xs[m * LSTR + c4 * 4] = v;
        }
        // stage W: 131 rows x 32 k = 1048 float4
#pragma unroll
        for (int q = 0; q < 5; ++q) {
            int lin = tid + q * 256;
            if (lin < CC * 8) {
                int r = lin >> 3, c4 = lin & 7;
                float4 v = *(const float4*)&W[(size_t)r * DD + k0 + c4 * 4];
                *(float4*)&ws[r * LSTR + c4 * 4] = v;
            }
        }
        __syncthreads();

#pragma unroll
        for (int k4 = 0; k4 < 8; ++k4) {
            float4 xr[8], wr[8], wt;
#pragma unroll
            for (int r = 0; r < 8; ++r)
                xr[r] = *(const float4*)&xs[(tm + 16 * r) * LSTR + k4 * 4];
#pragma unroll
            for (int c = 0; c < 8; ++c)
                wr[c] = *(const float4*)&ws[(tj + 16 * c) * LSTR + k4 * 4];
            wt = *(const float4*)&ws[(128 + tjt) * LSTR + k4 * 4];
#pragma unroll
            for (int r = 0; r < 8; ++r) {
#pragma unroll
                for (int c = 0; c < 8; ++c) {
                    acc[r][c] = fmaf(xr[r].x, wr[c].x, acc[r][c]);
                    acc[r][c] = fmaf(xr[r].y, wr[c].y, acc[r][c]);
                    acc[r][c] = fmaf(xr[r].z, wr[c].z, acc[r][c]);
                    acc[r][c] = fmaf(xr[r].w, wr[c].w, acc[r][c]);
                }
                acct[r] = fmaf(xr[r].x, wt.x, acct[r]);
                acct[r] = fmaf(xr[r].y, wt.y, acct[r]);
                acct[r] = fmaf(xr[r].z, wt.z, acct[r]);
                acct[r] = fmaf(xr[r].w, wt.w, acct[r]);
            }
        }
    }

    // epilogue: bias + direct stores (17 MB total, once per block)
#pragma unroll
    for (int c = 0; c < 8; ++c) {
        int j = tj + 16 * c;
        float bv = bias[j];
#pragma unroll
        for (int r = 0; r < 8; ++r)
            feats[(size_t)(m0 + tm + 16 * r) * CP + j] = acc[r][c] + bv;
    }
    if (tail) {
        int j = 128 + tj;
        float bv = bias[j];
#pragma unroll
        for (int r = 0; r < 8; ++r)
            feats[(size_t)(m0 + tm + 16 * r) * CP + j] = acct[r] + bv;
    }
}

// ---------------- Kernel 2: Viterbi forward (value-only), scores -> hist ----------------
// 64 blocks x 192 threads. T-row in 33 float4 VGPRs (fully unrolled, const-indexed).
__global__ __launch_bounds__(192, 1) void viterbi_fwd(
    const float* __restrict__ feats, const float* __restrict__ mask,
    const float* __restrict__ trans, float* __restrict__ hist)
{
    const int b = blockIdx.x;
    const int j = threadIdx.x;
    const int jr = (j < CC) ? j : (CC - 1);
    __shared__ float sbuf[2][CP];

    float4 Tr[33];
    {
        const float* trow = trans + (size_t)jr * CC;
#pragma unroll
        for (int i4 = 0; i4 < 32; ++i4) {
            Tr[i4].x = trow[i4 * 4 + 0];
            Tr[i4].y = trow[i4 * 4 + 1];
            Tr[i4].z = trow[i4 * 4 + 2];
            Tr[i4].w = trow[i4 * 4 + 3];
        }
        Tr[32].x = trow[128]; Tr[32].y = trow[129]; Tr[32].z = trow[130];
        Tr[32].w = NEGV;      // pad slot 131
    }

    if (j < CP) {
        sbuf[0][j] = (j == START_I) ? 0.f : NEGV;
        sbuf[1][j] = NEGV;                    // pad slot stays NEGV forever
    }
    float s_reg = (j == START_I) ? 0.f : NEGV;
    __syncthreads();

    const float* fb = feats + (size_t)b * LL * CP;
    const float* mb = mask + (size_t)b * LL;
    float* hb = hist + (size_t)b * LL * CP;
    const int jc = (j < CP) ? j : (CP - 1);

    float fv = fb[jc];
    float mv = mb[0];
    int cur = 0;
    float ns_prev = 0.f;

    for (int t = 0; t < LL; ++t) {
        // deferred history store (stays in flight: no vmcnt drain at barrier)
        if (t > 0 && j < CC) hb[(size_t)(t - 1) * CP + j] = ns_prev;
        // prefetch next feat/mask
        float fv_n = 0.f, mv_n = 1.f;
        if (t + 1 < LL) { fv_n = fb[(size_t)(t + 1) * CP + jc]; mv_n = mb[t + 1]; }

        const float4* s4 = (const float4*)sbuf[cur];
        float mx0 = -3.0e38f, mx1 = -3.0e38f;
#pragma unroll
        for (int i4 = 0; i4 < 33; ++i4) {
            float4 sv = s4[i4];
            float v0 = sv.x + Tr[i4].x;
            float v1 = sv.y + Tr[i4].y;
            float v2 = sv.z + Tr[i4].z;
            float v3 = sv.w + Tr[i4].w;
            mx0 = fmaxf(fmaxf(mx0, v0), v1);   // -> v_max3
            mx1 = fmaxf(fmaxf(mx1, v2), v3);
        }
        float best = fmaxf(mx0, mx1);
        float ns = (mv != 0.f) ? (best + fv) : s_reg;
        s_reg = ns;
        if (j < CC) sbuf[cur ^ 1][j] = ns;
        lds_barrier();
        ns_prev = ns;
        fv = fv_n; mv = mv_n;
        cur ^= 1;
    }
    if (j < CC) hb[(size_t)(LL - 1) * CP + j] = ns_prev;
}

// ---------------- Kernel 3: backpointer matrix, massively parallel recompute ----------------
// 4096 blocks (64 b x 64 t-chunks) x 192 threads. bp[b][t][j] = argmax_i(hist[t-1][i]+T[j,i])
// for t in 1..511 — same fp32 expression as forward => bit-identical argmax.
__global__ __launch_bounds__(192, 1) void bp_kernel(
    const float* __restrict__ hist, const float* __restrict__ trans,
    unsigned char* __restrict__ bp)
{
    const int b = blockIdx.x >> 6;
    const int tch = blockIdx.x & 63;
    const int j = threadIdx.x;
    const int jr = (j < CC) ? j : (CC - 1);
    __shared__ float hs[8 * CP];   // hist rows tch*8 .. tch*8+7 (= h[t-1] for t = t0..t0+7)

    {
        const float4* src = (const float4*)(hist + ((size_t)b * LL + tch * 8) * CP);
#pragma unroll
        for (int q = 0; q < 2; ++q) {
            int lin = threadIdx.x + q * 192;
            if (lin < (8 * CP) / 4) ((float4*)hs)[lin] = src[lin];
        }
    }

    float4 Tr[33];
    {
        const float* trow = trans + (size_t)jr * CC;
#pragma unroll
        for (int i4 = 0; i4 < 32; ++i4) {
            Tr[i4].x = trow[i4 * 4 + 0];
            Tr[i4].y = trow[i4 * 4 + 1];
            Tr[i4].z = trow[i4 * 4 + 2];
            Tr[i4].w = trow[i4 * 4 + 3];
        }
        Tr[32].x = trow[128]; Tr[32].y = trow[129]; Tr[32].z = trow[130];
        Tr[32].w = NEGV;
    }
    __syncthreads();

    float best[8];
    int idx[8];
#pragma unroll
    for (int tt = 0; tt < 8; ++tt) { best[tt] = -3.0e38f; idx[tt] = 0; }

#pragma unroll
    for (int i4 = 0; i4 < 33; ++i4) {
#pragma unroll
        for (int tt = 0; tt < 8; ++tt) {
            float4 hv = *(const float4*)&hs[tt * CP + i4 * 4];
            {
                float v = hv.x + Tr[i4].x;
                if (v > best[tt]) { best[tt] = v; idx[tt] = i4 * 4 + 0; }
            }
            {
                float v = hv.y + Tr[i4].y;
                if (v > best[tt]) { best[tt] = v; idx[tt] = i4 * 4 + 1; }
            }
            {
                float v = hv.z + Tr[i4].z;
                if (v > best[tt]) { best[tt] = v; idx[tt] = i4 * 4 + 2; }
            }
            if (i4 < 32) {
                float v = hv.w + Tr[i4].w;
                if (v > best[tt]) { best[tt] = v; idx[tt] = i4 * 4 + 3; }
            }
        }
    }

    const int t0 = tch * 8 + 1;
    if (j < CC) {
#pragma unroll
        for (int tt = 0; tt < 8; ++tt) {
            int t = t0 + tt;
            if (t < LL) bp[((size_t)b * LL + t) * CP + j] = (unsigned char)idx[tt];
        }
    }
}

// ---------------- Kernel 4: final argmax + u8 pointer-chase backtrack ----------------
__global__ __launch_bounds__(64, 1) void viterbi_btr(
    const float* __restrict__ hist, const float* __restrict__ trans,
    const unsigned char* __restrict__ bp,
    float* __restrict__ out_score, float* __restrict__ out_path)
{
    const int b = blockIdx.x;
    const int lane = threadIdx.x;
    const float* hb = hist + ((size_t)b * LL + (LL - 1)) * CP;
    const float* ts = trans + (size_t)STOP_I * CC;

    float v0 = hb[lane] + ts[lane];
    float v1 = hb[lane + 64] + ts[lane + 64];
    float v2 = (lane < 3) ? (hb[lane + 128] + ts[lane + 128]) : -3.0e38f;

    float best = v0; int idx = lane;
    if (v1 > best) { best = v1; idx = lane + 64; }
    if (v2 > best) { best = v2; idx = lane + 128; }
#pragma unroll
    for (int off = 32; off >= 1; off >>= 1) {
        float ob = __shfl_xor(best, off, 64);
        int   oi = __shfl_xor(idx, off, 64);
        if (ob > best || (ob == best && oi < idx)) { best = ob; idx = oi; }
    }

    if (lane == 0) {
        out_score[b] = best;
        float* op = out_path + (size_t)b * LL;
        op[LL - 1] = (float)idx;
        int tag = idx;
        const unsigned char* bpb = bp + (size_t)b * LL * CP;
        for (int t = LL - 1; t >= 1; --t) {
            tag = bpb[(size_t)t * CP + tag];
            op[t - 1] = (float)tag;
        }
    }
}

extern "C" void kernel_launch(void* const* d_in, const int* in_sizes, int n_in,
                              void* d_out, int out_size, void* d_ws, size_t ws_size,
                              hipStream_t stream)
{
    const float* x     = (const float*)d_in[0];
    const float* mask  = (const float*)d_in[1];
    const float* W     = (const float*)d_in[2];
    const float* bias  = (const float*)d_in[3];
    const float* trans = (const float*)d_in[4];

    float* feats = (float*)d_ws;                                   // 32768*132 f32
    float* hist  = feats + (size_t)BB * LL * CP;                   // 64*512*132 f32
    unsigned char* bp = (unsigned char*)(hist + (size_t)BB * LL * CP);  // 64*512*132 u8
    float* out_score = (float*)d_out;
    float* out_path  = out_score + BB;

    hipLaunchKernelGGL(gemm_feats, dim3((BB * LL) / GM), dim3(256), 0, stream, x, W, bias, feats);
    hipLaunchKernelGGL(viterbi_fwd, dim3(BB), dim3(192), 0, stream, feats, mask, trans, hist);
    hipLaunchKernelGGL(bp_kernel, dim3(BB * 64), dim3(192), 0, stream, hist, trans, bp);
    hipLaunchKernelGGL(viterbi_btr, dim3(BB), dim3(64), 0, stream, hist, trans, bp, out_score, out_path);
}

// Round 3
// 781.090 us; speedup vs baseline: 1.6156x; 1.6156x over previous
//
#include <hip/hip_runtime.h>

#define BB 64
#define LL 512
#define DD 1024
#define CC 131
#define CP 132
#define START_I 129
#define STOP_I 130
#define NEGV -10000.0f

// Raw workgroup barrier: makes LDS writes visible without draining vmcnt
// (so global stores/prefetches stay in flight across steps).
__device__ __forceinline__ void lds_barrier() {
    asm volatile("s_waitcnt lgkmcnt(0)" ::: "memory");
    __builtin_amdgcn_s_barrier();
    __builtin_amdgcn_sched_barrier(0);
}

// ---------------- Kernel 1: feats[m][c] = dot(x[m,:], W[c,:]) + b[c] ----------------
// 256 blocks x 256 threads. Block tile 128m x 131j, thread tile 8m x 8j (+3-col tail
// for tj<3). LDS [row][k] stride 36 floats (144B, 16B-aligned, 2-way banks = free).
#define GM 128
#define GK 32
#define LSTR 36

__global__ __launch_bounds__(256, 1) void gemm_feats(
    const float* __restrict__ x, const float* __restrict__ W,
    const float* __restrict__ bias, float* __restrict__ feats)
{
    __shared__ float xs[GM * LSTR];   // [m][k]
    __shared__ float ws[CP * LSTR];   // [j][k]

    const int tid = threadIdx.x;
    const int m0 = blockIdx.x * GM;
    const int tm = tid & 15;          // m-thread  (rows tm + 16r)
    const int tj = (tid >> 4) & 15;   // j-thread  (cols tj + 16c)
    const bool tail = (tj < 3);
    const int tjt = (tj < 3) ? tj : 2;

    float acc[8][8];
    float acct[8];
#pragma unroll
    for (int r = 0; r < 8; ++r) {
        acct[r] = 0.f;
#pragma unroll
        for (int c = 0; c < 8; ++c) acc[r][c] = 0.f;
    }

    for (int kc = 0; kc < DD / GK; ++kc) {
        const int k0 = kc * GK;
        if (kc) __syncthreads();
        // stage x: 128 rows x 32 k = 1024 float4 (coalesced global, aligned LDS f4)
#pragma unroll
        for (int q = 0; q < 4; ++q) {
            int lin = tid + q * 256;
            int m = lin >> 3, c4 = lin & 7;
            float4 v = *(const float4*)&x[(size_t)(m0 + m) * DD + k0 + c4 * 4];
            *(float4*)&xs[m * LSTR + c4 * 4] = v;
        }
        // stage W: 131 rows x 32 k = 1048 float4
#pragma unroll
        for (int q = 0; q < 5; ++q) {
            int lin = tid + q * 256;
            if (lin < CC * 8) {
                int r = lin >> 3, c4 = lin & 7;
                float4 v = *(const float4*)&W[(size_t)r * DD + k0 + c4 * 4];
                *(float4*)&ws[r * LSTR + c4 * 4] = v;
            }
        }
        __syncthreads();

#pragma unroll
        for (int k4 = 0; k4 < 8; ++k4) {
            float4 xr[8], wr[8], wt;
#pragma unroll
            for (int r = 0; r < 8; ++r)
                xr[r] = *(const float4*)&xs[(tm + 16 * r) * LSTR + k4 * 4];
#pragma unroll
            for (int c = 0; c < 8; ++c)
                wr[c] = *(const float4*)&ws[(tj + 16 * c) * LSTR + k4 * 4];
            wt = *(const float4*)&ws[(128 + tjt) * LSTR + k4 * 4];
#pragma unroll
            for (int r = 0; r < 8; ++r) {
#pragma unroll
                for (int c = 0; c < 8; ++c) {
                    acc[r][c] = fmaf(xr[r].x, wr[c].x, acc[r][c]);
                    acc[r][c] = fmaf(xr[r].y, wr[c].y, acc[r][c]);
                    acc[r][c] = fmaf(xr[r].z, wr[c].z, acc[r][c]);
                    acc[r][c] = fmaf(xr[r].w, wr[c].w, acc[r][c]);
                }
                acct[r] = fmaf(xr[r].x, wt.x, acct[r]);
                acct[r] = fmaf(xr[r].y, wt.y, acct[r]);
                acct[r] = fmaf(xr[r].z, wt.z, acct[r]);
                acct[r] = fmaf(xr[r].w, wt.w, acct[r]);
            }
        }
    }

    // epilogue: bias + direct stores
#pragma unroll
    for (int c = 0; c < 8; ++c) {
        int j = tj + 16 * c;
        float bv = bias[j];
#pragma unroll
        for (int r = 0; r < 8; ++r)
            feats[(size_t)(m0 + tm + 16 * r) * CP + j] = acc[r][c] + bv;
    }
    if (tail) {
        int j = 128 + tj;
        float bv = bias[j];
#pragma unroll
        for (int r = 0; r < 8; ++r)
            feats[(size_t)(m0 + tm + 16 * r) * CP + j] = acct[r] + bv;
    }
}

// ---------------- Kernel 2: Viterbi forward (value-only), scores -> hist ----------------
// 64 blocks x 192 threads. T-row in 33 float4 VGPRs (fully unrolled, const-indexed).
__global__ __launch_bounds__(192, 1) void viterbi_fwd(
    const float* __restrict__ feats, const float* __restrict__ mask,
    const float* __restrict__ trans, float* __restrict__ hist)
{
    const int b = blockIdx.x;
    const int j = threadIdx.x;
    const int jr = (j < CC) ? j : (CC - 1);
    __shared__ float sbuf[2][CP];

    float4 Tr[33];
    {
        const float* trow = trans + (size_t)jr * CC;
#pragma unroll
        for (int i4 = 0; i4 < 32; ++i4) {
            Tr[i4].x = trow[i4 * 4 + 0];
            Tr[i4].y = trow[i4 * 4 + 1];
            Tr[i4].z = trow[i4 * 4 + 2];
            Tr[i4].w = trow[i4 * 4 + 3];
        }
        Tr[32].x = trow[128]; Tr[32].y = trow[129]; Tr[32].z = trow[130];
        Tr[32].w = NEGV;      // pad slot 131
    }

    if (j < CP) {
        sbuf[0][j] = (j == START_I) ? 0.f : NEGV;
        sbuf[1][j] = NEGV;                    // pad slot stays NEGV forever
    }
    float s_reg = (j == START_I) ? 0.f : NEGV;
    __syncthreads();

    const float* fb = feats + (size_t)b * LL * CP;
    const float* mb = mask + (size_t)b * LL;
    float* hb = hist + (size_t)b * LL * CP;
    const int jc = (j < CP) ? j : (CP - 1);

    float fv = fb[jc];
    float mv = mb[0];
    int cur = 0;
    float ns_prev = 0.f;

    for (int t = 0; t < LL; ++t) {
        // deferred history store (stays in flight: no vmcnt drain at barrier)
        if (t > 0 && j < CC) hb[(size_t)(t - 1) * CP + j] = ns_prev;
        // prefetch next feat/mask
        float fv_n = 0.f, mv_n = 1.f;
        if (t + 1 < LL) { fv_n = fb[(size_t)(t + 1) * CP + jc]; mv_n = mb[t + 1]; }

        const float4* s4 = (const float4*)sbuf[cur];
        float mx0 = -3.0e38f, mx1 = -3.0e38f;
#pragma unroll
        for (int i4 = 0; i4 < 33; ++i4) {
            float4 sv = s4[i4];
            float v0 = sv.x + Tr[i4].x;
            float v1 = sv.y + Tr[i4].y;
            float v2 = sv.z + Tr[i4].z;
            float v3 = sv.w + Tr[i4].w;
            mx0 = fmaxf(fmaxf(mx0, v0), v1);   // -> v_max3
            mx1 = fmaxf(fmaxf(mx1, v2), v3);
        }
        float best = fmaxf(mx0, mx1);
        float ns = (mv != 0.f) ? (best + fv) : s_reg;
        s_reg = ns;
        if (j < CC) sbuf[cur ^ 1][j] = ns;
        lds_barrier();
        ns_prev = ns;
        fv = fv_n; mv = mv_n;
        cur ^= 1;
    }
    if (j < CC) hb[(size_t)(LL - 1) * CP + j] = ns_prev;
}

// ---------------- Kernel 3: backpointer matrix, LDS-resident T (no register row) ----------------
// Block = 32 j's x 8 timesteps = 256 threads. T rows in LDS [32][136] (2-way banks = free),
// hist rows in LDS [8][132]. Scan i DESCENDING with >= (== first-max tie-break, matches argmax).
__global__ __launch_bounds__(256, 4) void bp_kernel(
    const float* __restrict__ hist, const float* __restrict__ trans,
    unsigned char* __restrict__ bp)
{
    const int b  = blockIdx.x / 5;
    const int jc = blockIdx.x % 5;
    const int tc = blockIdx.y;
    const int tid = threadIdx.x;
    const int j0 = jc * 32;

    __shared__ float Ts[32][136];
    __shared__ float hs[8][132];

    // stage T rows j0..j0+31 (scalar, coalesced; rows beyond 130 skipped)
    for (int q = 0; q < 17; ++q) {
        int lin = tid + q * 256;
        if (lin < 32 * CC) {
            int r = lin / CC, i = lin - r * CC;
            if (j0 + r < CC) Ts[r][i] = trans[(size_t)(j0 + r) * CC + i];
        }
    }
    // stage hist rows tc*8 .. tc*8+7 (float4)
    {
        const float4* src = (const float4*)(hist + ((size_t)b * LL + tc * 8) * CP);
#pragma unroll
        for (int q = 0; q < 2; ++q) {
            int lin = tid + q * 256;
            if (lin < (8 * CP) / 4) ((float4*)hs)[lin] = src[lin];
        }
    }
    __syncthreads();

    const int jl = tid & 31;
    const int tt = tid >> 5;
    const int j = j0 + jl;
    const int t = tc * 8 + tt + 1;
    if (j >= CC || t >= LL) return;

    float best; int idx;
    {   // i = 130, 129, 128 (descending start)
        float4 tv = *(const float4*)&Ts[jl][128];
        float4 hv = *(const float4*)&hs[tt][128];
        best = hv.z + tv.z; idx = 130;
        float v;
        v = hv.y + tv.y; if (v >= best) { best = v; idx = 129; }
        v = hv.x + tv.x; if (v >= best) { best = v; idx = 128; }
    }
#pragma unroll
    for (int i4 = 31; i4 >= 0; --i4) {
        float4 tv = *(const float4*)&Ts[jl][i4 * 4];
        float4 hv = *(const float4*)&hs[tt][i4 * 4];
        float v;
        v = hv.w + tv.w; if (v >= best) { best = v; idx = i4 * 4 + 3; }
        v = hv.z + tv.z; if (v >= best) { best = v; idx = i4 * 4 + 2; }
        v = hv.y + tv.y; if (v >= best) { best = v; idx = i4 * 4 + 1; }
        v = hv.x + tv.x; if (v >= best) { best = v; idx = i4 * 4 + 0; }
    }
    bp[((size_t)b * LL + t) * CP + j] = (unsigned char)idx;
}

// ---------------- Kernel 4: final argmax + LDS-streamed u8 backtrack ----------------
// 64 blocks x 64 threads (1 wave). Row index t is known in advance -> prefetch 8-row
// chunks into LDS (reg-staged, double-buffered); chase reads become ~50cyc LDS hits.
__global__ __launch_bounds__(64, 1) void viterbi_btr(
    const float* __restrict__ hist, const float* __restrict__ trans,
    const unsigned char* __restrict__ bp,
    float* __restrict__ out_score, float* __restrict__ out_path)
{
    const int b = blockIdx.x;
    const int lane = threadIdx.x;
    const float* hb = hist + ((size_t)b * LL + (LL - 1)) * CP;
    const float* ts = trans + (size_t)STOP_I * CC;

    float v0 = hb[lane] + ts[lane];
    float v1 = hb[lane + 64] + ts[lane + 64];
    float v2 = (lane < 3) ? (hb[lane + 128] + ts[lane + 128]) : -3.0e38f;

    float best = v0; int idx = lane;
    if (v1 > best) { best = v1; idx = lane + 64; }
    if (v2 > best) { best = v2; idx = lane + 128; }
#pragma unroll
    for (int off = 32; off >= 1; off >>= 1) {
        float ob = __shfl_xor(best, off, 64);
        int   oi = __shfl_xor(idx, off, 64);
        if (ob > best || (ob == best && oi < idx)) { best = ob; idx = oi; }
    }

    float* op = out_path + (size_t)b * LL;
    if (lane == 0) {
        out_score[b] = best;
        op[LL - 1] = (float)idx;
    }
    int tag = idx;   // all lanes hold the global argmax after the butterfly

    __shared__ unsigned char buf[2][1088];   // 8 rows x 132 = 1056 B per chunk
    const unsigned char* bpb = bp + (size_t)b * LL * CP;

    // preload chunk 63 (rows t=504..511) into buf[1]
    {
        const unsigned int* src = (const unsigned int*)(bpb + (size_t)504 * CP);
        unsigned int* dst = (unsigned int*)buf[1];
#pragma unroll
        for (int q = 0; q < 5; ++q) {
            int lin = lane + q * 64;
            if (lin < 264) dst[lin] = src[lin];
        }
    }
    lds_barrier();

    int cur = 1;
    for (int k = 63; k >= 0; --k) {
        // issue next chunk's loads (overlap with chase)
        unsigned int r0 = 0, r1 = 0, r2 = 0, r3 = 0, r4 = 0;
        if (k > 0) {
            const unsigned int* src = (const unsigned int*)(bpb + (size_t)(k - 1) * 8 * CP);
            r0 = src[lane];
            r1 = src[lane + 64];
            r2 = src[lane + 128];
            r3 = src[lane + 192];
            if (lane < 8) r4 = src[lane + 256];
        }
        // chase 8 steps (t = 8k+7 .. 8k), LDS broadcast reads
        const unsigned char* cb = buf[cur];
#pragma unroll
        for (int s = 7; s >= 0; --s) {
            int t = k * 8 + s;
            if (t >= 1) {
                tag = cb[s * CP + tag];
                if (lane == 0) op[t - 1] = (float)tag;
            }
        }
        // write next chunk and publish (lgkm-only barrier keeps stores pipelined)
        if (k > 0) {
            unsigned int* dst = (unsigned int*)buf[cur ^ 1];
            dst[lane] = r0;
            dst[lane + 64] = r1;
            dst[lane + 128] = r2;
            dst[lane + 192] = r3;
            if (lane < 8) dst[lane + 256] = r4;
            lds_barrier();
        }
        cur ^= 1;
    }
}

extern "C" void kernel_launch(void* const* d_in, const int* in_sizes, int n_in,
                              void* d_out, int out_size, void* d_ws, size_t ws_size,
                              hipStream_t stream)
{
    const float* x     = (const float*)d_in[0];
    const float* mask  = (const float*)d_in[1];
    const float* W     = (const float*)d_in[2];
    const float* bias  = (const float*)d_in[3];
    const float* trans = (const float*)d_in[4];

    float* feats = (float*)d_ws;                                   // 64*512*132 f32
    float* hist  = feats + (size_t)BB * LL * CP;                   // 64*512*132 f32
    unsigned char* bp = (unsigned char*)(hist + (size_t)BB * LL * CP);  // 64*512*132 u8
    float* out_score = (float*)d_out;
    float* out_path  = out_score + BB;

    hipLaunchKernelGGL(gemm_feats, dim3((BB * LL) / GM), dim3(256), 0, stream, x, W, bias, feats);
    hipLaunchKernelGGL(viterbi_fwd, dim3(BB), dim3(192), 0, stream, feats, mask, trans, hist);
    hipLaunchKernelGGL(bp_kernel, dim3(BB * 5, 64), dim3(256), 0, stream, hist, trans, bp);
    hipLaunchKernelGGL(viterbi_btr, dim3(BB), dim3(64), 0, stream, hist, trans, bp, out_score, out_path);
}